// Round 1
// baseline (169.668 us; speedup 1.0000x reference)
//
#include <hip/hip_runtime.h>
#include <math.h>

#define NPTS 4096
#define NB 16
#define KNN 5
#define RADIUSF 0.07f
#define HF 0.03f
#define EPSF 1e-12f
#define THREADS 256
#define CHUNKS (NPTS / THREADS)   // 16 chunks per batch

// Insert candidate d into sorted-ascending b0..b5 (keep 6 smallest).
#define INSERT6(d)                         \
    do {                                   \
        b5 = fminf(b5, fmaxf(b4, (d)));    \
        b4 = fminf(b4, fmaxf(b3, (d)));    \
        b3 = fminf(b3, fmaxf(b2, (d)));    \
        b2 = fminf(b2, fmaxf(b1, (d)));    \
        b1 = fminf(b1, fmaxf(b0, (d)));    \
        b0 = fminf(b0, (d));               \
    } while (0)

__global__ __launch_bounds__(THREADS) void repulsion_knn_kernel(
    const float* __restrict__ pred, float* __restrict__ partial)
{
    __shared__ __align__(16) float pts[NPTS * 3];
    __shared__ float red[THREADS / 64];

    const int b     = blockIdx.x >> 4;   // / CHUNKS
    const int chunk = blockIdx.x & 15;   // % CHUNKS
    const float* pb = pred + (size_t)b * NPTS * 3;

    // Stage this batch's points (48 KB) into LDS, coalesced float4 loads.
    for (int i = threadIdx.x; i < NPTS * 3 / 4; i += THREADS) {
        ((float4*)pts)[i] = ((const float4*)pb)[i];
    }
    __syncthreads();

    const int n = chunk * THREADS + threadIdx.x;
    const float qx = pts[3 * n + 0];
    const float qy = pts[3 * n + 1];
    const float qz = pts[3 * n + 2];

    // 6 smallest squared distances (self included; self == 0 exactly -> b0).
    float b0 = 1e30f, b1 = 1e30f, b2 = 1e30f,
          b3 = 1e30f, b4 = 1e30f, b5 = 1e30f;

    const float4* p4 = (const float4*)pts;
    #pragma unroll 4
    for (int g = 0; g < NPTS / 4; ++g) {
        // 4 points = 12 floats = 3 wave-uniform ds_read_b128 (broadcast).
        const float4 A = p4[3 * g + 0];
        const float4 B = p4[3 * g + 1];
        const float4 C = p4[3 * g + 2];

        float dx, dy, dz;
        dx = A.x - qx; dy = A.y - qy; dz = A.z - qz;
        const float d0 = fmaf(dx, dx, fmaf(dy, dy, dz * dz));
        dx = A.w - qx; dy = B.x - qy; dz = B.y - qz;
        const float d1 = fmaf(dx, dx, fmaf(dy, dy, dz * dz));
        dx = B.z - qx; dy = B.w - qy; dz = C.x - qz;
        const float d2 = fmaf(dx, dx, fmaf(dy, dy, dz * dz));
        dx = C.y - qx; dy = C.z - qy; dz = C.w - qz;
        const float d3 = fmaf(dx, dx, fmaf(dy, dy, dz * dz));

        const float mn = fminf(fminf(d0, d1), fminf(d2, d3));
        if (mn < b5) {   // rare after warm-up: ~k*ln(N/k) inserts per thread
            INSERT6(d0);
            INSERT6(d1);
            INSERT6(d2);
            INSERT6(d3);
        }
    }

    // b0 == self (exactly 0): drop it. Neighbors are b1..b5.
    float loss = 0.0f;
    {
        const float nb[5] = { b1, b2, b3, b4, b5 };
        #pragma unroll
        for (int i = 0; i < 5; ++i) {
            const float d  = sqrtf(fmaxf(nb[i], EPSF));
            const float t  = d / HF;
            loss += (RADIUSF - d) * expf(-t * t);
        }
    }

    // Deterministic block reduction: wave shuffle -> LDS -> thread 0.
    #pragma unroll
    for (int off = 32; off > 0; off >>= 1)
        loss += __shfl_down(loss, off, 64);

    const int wave = threadIdx.x >> 6;
    const int lane = threadIdx.x & 63;
    if (lane == 0) red[wave] = loss;
    __syncthreads();
    if (threadIdx.x == 0) {
        float s = 0.0f;
        #pragma unroll
        for (int w = 0; w < THREADS / 64; ++w) s += red[w];
        partial[blockIdx.x] = s;
    }
}

__global__ void repulsion_reduce_kernel(const float* __restrict__ partial,
                                        float* __restrict__ out)
{
    const int b = threadIdx.x;
    if (b < NB) {
        float s = 0.0f;
        #pragma unroll
        for (int i = 0; i < CHUNKS; ++i) s += partial[b * CHUNKS + i];
        out[b] = s * (1.0f / ((float)NPTS * (float)KNN));
    }
}

extern "C" void kernel_launch(void* const* d_in, const int* in_sizes, int n_in,
                              void* d_out, int out_size, void* d_ws, size_t ws_size,
                              hipStream_t stream)
{
    const float* pred = (const float*)d_in[0];
    float* out        = (float*)d_out;
    float* partial    = (float*)d_ws;   // NB*CHUNKS = 256 floats

    repulsion_knn_kernel<<<dim3(NB * CHUNKS), dim3(THREADS), 0, stream>>>(pred, partial);
    repulsion_reduce_kernel<<<dim3(1), dim3(64), 0, stream>>>(partial, out);
}

// Round 2
// 77.546 us; speedup vs baseline: 2.1880x; 2.1880x over previous
//
#include <hip/hip_runtime.h>
#include <math.h>

#define NPTS 4096
#define NB 16
#define THREADS 256
#define RADIUSF 0.07f
#define HF 0.03f
#define EPSF 1e-12f

// Insert d into sorted-ascending 6-list: b0'=min(b0,d), bk'=med3(d,b(k-1),bk).
// 6 independent VALU ops (v_min + 5x v_med3), no chain.
#define INS6(L0,L1,L2,L3,L4,L5,dd) do {                         \
    const float _d  = (dd);                                     \
    const float _n0 = fminf((L0), _d);                          \
    const float _n1 = __builtin_amdgcn_fmed3f(_d, (L0), (L1));  \
    const float _n2 = __builtin_amdgcn_fmed3f(_d, (L1), (L2));  \
    const float _n3 = __builtin_amdgcn_fmed3f(_d, (L2), (L3));  \
    const float _n4 = __builtin_amdgcn_fmed3f(_d, (L3), (L4));  \
    const float _n5 = __builtin_amdgcn_fmed3f(_d, (L4), (L5));  \
    (L0)=_n0; (L1)=_n1; (L2)=_n2; (L3)=_n3; (L4)=_n4; (L5)=_n5; \
} while (0)

// ---------------------------------------------------------------------------
// Pass 1: per (batch, cand-split, query-chunk) block, scan NCAND candidates
// and emit the 6 smallest squared distances per query (self included, ==0).
// ---------------------------------------------------------------------------
template<int NCAND>
__global__ __launch_bounds__(THREADS, 4) void knn_split_kernel(
    const float* __restrict__ pred, float* __restrict__ cand6)
{
    constexpr int S = NPTS / NCAND;              // candidate splits
    __shared__ __align__(16) float sx[NCAND];
    __shared__ __align__(16) float sy[NCAND];
    __shared__ __align__(16) float sz[NCAND];

    const int bid   = blockIdx.x;
    const int chunk = bid & 15;                  // query chunk (16 of 256)
    const int cs    = (bid >> 4) % S;            // candidate split
    const int b     = bid / (16 * S);            // batch

    const float* pb  = pred + (size_t)b * NPTS * 3;
    const float* src = pb + (size_t)cs * NCAND * 3;

    // Stage AoS (x,y,z interleaved) -> SoA in LDS. One-time cost.
    for (int p = threadIdx.x; p < NCAND; p += THREADS) {
        sx[p] = src[3 * p + 0];
        sy[p] = src[3 * p + 1];
        sz[p] = src[3 * p + 2];
    }
    __syncthreads();

    const int n = chunk * THREADS + threadIdx.x; // query index in batch
    const float qx = pb[3 * n + 0];
    const float qy = pb[3 * n + 1];
    const float qz = pb[3 * n + 2];

    // Two interleaved top-6 lists (even/odd candidates) for ILP.
    float A0=1e30f,A1=1e30f,A2=1e30f,A3=1e30f,A4=1e30f,A5=1e30f;
    float B0=1e30f,B1=1e30f,B2=1e30f,B3=1e30f,B4=1e30f,B5=1e30f;

    const float4* X4 = (const float4*)sx;
    const float4* Y4 = (const float4*)sy;
    const float4* Z4 = (const float4*)sz;

    #pragma unroll 2
    for (int g = 0; g < NCAND / 4; ++g) {
        const float4 X = X4[g];                  // 3 broadcast ds_read_b128
        const float4 Y = Y4[g];
        const float4 Z = Z4[g];

        const float dx0 = X.x - qx, dy0 = Y.x - qy, dz0 = Z.x - qz;
        const float dx1 = X.y - qx, dy1 = Y.y - qy, dz1 = Z.y - qz;
        const float dx2 = X.z - qx, dy2 = Y.z - qy, dz2 = Z.z - qz;
        const float dx3 = X.w - qx, dy3 = Y.w - qy, dz3 = Z.w - qz;

        const float d0 = fmaf(dz0, dz0, fmaf(dy0, dy0, dx0 * dx0));
        const float d1 = fmaf(dz1, dz1, fmaf(dy1, dy1, dx1 * dx1));
        const float d2 = fmaf(dz2, dz2, fmaf(dy2, dy2, dx2 * dx2));
        const float d3 = fmaf(dz3, dz3, fmaf(dy3, dy3, dx3 * dx3));

        INS6(A0,A1,A2,A3,A4,A5, d0);             // no branch: always insert
        INS6(B0,B1,B2,B3,B4,B5, d1);
        INS6(A0,A1,A2,A3,A4,A5, d2);
        INS6(B0,B1,B2,B3,B4,B5, d3);
    }

    // Merge B into A -> 6 smallest of this split.
    INS6(A0,A1,A2,A3,A4,A5, B0);
    INS6(A0,A1,A2,A3,A4,A5, B1);
    INS6(A0,A1,A2,A3,A4,A5, B2);
    INS6(A0,A1,A2,A3,A4,A5, B3);
    INS6(A0,A1,A2,A3,A4,A5, B4);
    INS6(A0,A1,A2,A3,A4,A5, B5);

    // Layout: cand6[((b*S+cs)*6 + j)*NPTS + n]  (coalesced stores & loads)
    float* o = cand6 + ((size_t)(b * S + cs) * 6) * NPTS + n;
    o[0 * NPTS] = A0; o[1 * NPTS] = A1; o[2 * NPTS] = A2;
    o[3 * NPTS] = A3; o[4 * NPTS] = A4; o[5 * NPTS] = A5;
}

// ---------------------------------------------------------------------------
// Pass 2: merge the S per-split 6-lists per query, drop self (exact 0),
// evaluate the loss on the 5 NN, block-reduce to partial sums.
// ---------------------------------------------------------------------------
template<int S>
__global__ __launch_bounds__(THREADS) void merge_loss_kernel(
    const float* __restrict__ cand6, float* __restrict__ partial)
{
    __shared__ float red[THREADS / 64];
    const int q = blockIdx.x * THREADS + threadIdx.x;   // global query id
    const int b = q >> 12;                              // /4096
    const int n = q & (NPTS - 1);

    float L0=1e30f,L1=1e30f,L2=1e30f,L3=1e30f,L4=1e30f,L5=1e30f;
    #pragma unroll
    for (int cs = 0; cs < S; ++cs) {
        const float* p = cand6 + ((size_t)(b * S + cs) * 6) * NPTS + n;
        INS6(L0,L1,L2,L3,L4,L5, p[0 * NPTS]);
        INS6(L0,L1,L2,L3,L4,L5, p[1 * NPTS]);
        INS6(L0,L1,L2,L3,L4,L5, p[2 * NPTS]);
        INS6(L0,L1,L2,L3,L4,L5, p[3 * NPTS]);
        INS6(L0,L1,L2,L3,L4,L5, p[4 * NPTS]);
        INS6(L0,L1,L2,L3,L4,L5, p[5 * NPTS]);
    }

    // L0 == self (exactly 0): drop. Neighbors are L1..L5.
    float loss = 0.0f;
    {
        const float nb[5] = { L1, L2, L3, L4, L5 };
        #pragma unroll
        for (int i = 0; i < 5; ++i) {
            const float d = sqrtf(fmaxf(nb[i], EPSF));
            const float t = d / HF;
            loss += (RADIUSF - d) * expf(-t * t);
        }
    }

    #pragma unroll
    for (int off = 32; off > 0; off >>= 1)
        loss += __shfl_down(loss, off, 64);

    const int wave = threadIdx.x >> 6;
    const int lane = threadIdx.x & 63;
    if (lane == 0) red[wave] = loss;
    __syncthreads();
    if (threadIdx.x == 0) {
        float s = 0.0f;
        #pragma unroll
        for (int w = 0; w < THREADS / 64; ++w) s += red[w];
        partial[blockIdx.x] = s;   // block = 256 consecutive queries
    }
}

__global__ void final_reduce_kernel(const float* __restrict__ partial,
                                    float* __restrict__ out)
{
    const int b = threadIdx.x;
    if (b < NB) {
        float s = 0.0f;
        #pragma unroll
        for (int i = 0; i < 16; ++i) s += partial[b * 16 + i];
        out[b] = s * (1.0f / ((float)NPTS * 5.0f));
    }
}

// ---------------------------------------------------------------------------
// Emergency path (tiny workspace): monolithic, loss computed in-kernel.
// ---------------------------------------------------------------------------
__global__ __launch_bounds__(THREADS) void mono_kernel(
    const float* __restrict__ pred, float* __restrict__ partial)
{
    __shared__ __align__(16) float sx[NPTS];
    __shared__ __align__(16) float sy[NPTS];
    __shared__ __align__(16) float sz[NPTS];
    __shared__ float red[THREADS / 64];

    const int b     = blockIdx.x >> 4;
    const int chunk = blockIdx.x & 15;
    const float* pb = pred + (size_t)b * NPTS * 3;

    for (int p = threadIdx.x; p < NPTS; p += THREADS) {
        sx[p] = pb[3 * p + 0]; sy[p] = pb[3 * p + 1]; sz[p] = pb[3 * p + 2];
    }
    __syncthreads();

    const int n = chunk * THREADS + threadIdx.x;
    const float qx = pb[3 * n], qy = pb[3 * n + 1], qz = pb[3 * n + 2];

    float A0=1e30f,A1=1e30f,A2=1e30f,A3=1e30f,A4=1e30f,A5=1e30f;
    float B0=1e30f,B1=1e30f,B2=1e30f,B3=1e30f,B4=1e30f,B5=1e30f;

    const float4* X4 = (const float4*)sx;
    const float4* Y4 = (const float4*)sy;
    const float4* Z4 = (const float4*)sz;

    #pragma unroll 2
    for (int g = 0; g < NPTS / 4; ++g) {
        const float4 X = X4[g], Y = Y4[g], Z = Z4[g];
        const float dx0 = X.x - qx, dy0 = Y.x - qy, dz0 = Z.x - qz;
        const float dx1 = X.y - qx, dy1 = Y.y - qy, dz1 = Z.y - qz;
        const float dx2 = X.z - qx, dy2 = Y.z - qy, dz2 = Z.z - qz;
        const float dx3 = X.w - qx, dy3 = Y.w - qy, dz3 = Z.w - qz;
        const float d0 = fmaf(dz0, dz0, fmaf(dy0, dy0, dx0 * dx0));
        const float d1 = fmaf(dz1, dz1, fmaf(dy1, dy1, dx1 * dx1));
        const float d2 = fmaf(dz2, dz2, fmaf(dy2, dy2, dx2 * dx2));
        const float d3 = fmaf(dz3, dz3, fmaf(dy3, dy3, dx3 * dx3));
        INS6(A0,A1,A2,A3,A4,A5, d0);
        INS6(B0,B1,B2,B3,B4,B5, d1);
        INS6(A0,A1,A2,A3,A4,A5, d2);
        INS6(B0,B1,B2,B3,B4,B5, d3);
    }
    INS6(A0,A1,A2,A3,A4,A5, B0);
    INS6(A0,A1,A2,A3,A4,A5, B1);
    INS6(A0,A1,A2,A3,A4,A5, B2);
    INS6(A0,A1,A2,A3,A4,A5, B3);
    INS6(A0,A1,A2,A3,A4,A5, B4);
    INS6(A0,A1,A2,A3,A4,A5, B5);

    float loss = 0.0f;
    {
        const float nb[5] = { A1, A2, A3, A4, A5 };
        #pragma unroll
        for (int i = 0; i < 5; ++i) {
            const float d = sqrtf(fmaxf(nb[i], EPSF));
            const float t = d / HF;
            loss += (RADIUSF - d) * expf(-t * t);
        }
    }
    #pragma unroll
    for (int off = 32; off > 0; off >>= 1)
        loss += __shfl_down(loss, off, 64);
    const int wave = threadIdx.x >> 6;
    const int lane = threadIdx.x & 63;
    if (lane == 0) red[wave] = loss;
    __syncthreads();
    if (threadIdx.x == 0) {
        float s = 0.0f;
        #pragma unroll
        for (int w = 0; w < THREADS / 64; ++w) s += red[w];
        partial[blockIdx.x] = s;
    }
}

extern "C" void kernel_launch(void* const* d_in, const int* in_sizes, int n_in,
                              void* d_out, int out_size, void* d_ws, size_t ws_size,
                              hipStream_t stream)
{
    const float* pred = (const float*)d_in[0];
    float* out        = (float*)d_out;

    const size_t f6 = (size_t)NB * 6 * NPTS;     // floats per S=1 list set

    if (ws_size >= (f6 * 4 + 256) * sizeof(float)) {
        float* cand6   = (float*)d_ws;
        float* partial = cand6 + f6 * 4;
        knn_split_kernel<1024><<<dim3(NB * 4 * 16), dim3(THREADS), 0, stream>>>(pred, cand6);
        merge_loss_kernel<4><<<dim3(256), dim3(THREADS), 0, stream>>>(cand6, partial);
        final_reduce_kernel<<<dim3(1), dim3(64), 0, stream>>>(partial, out);
    } else if (ws_size >= (f6 * 2 + 256) * sizeof(float)) {
        float* cand6   = (float*)d_ws;
        float* partial = cand6 + f6 * 2;
        knn_split_kernel<2048><<<dim3(NB * 2 * 16), dim3(THREADS), 0, stream>>>(pred, cand6);
        merge_loss_kernel<2><<<dim3(256), dim3(THREADS), 0, stream>>>(cand6, partial);
        final_reduce_kernel<<<dim3(1), dim3(64), 0, stream>>>(partial, out);
    } else if (ws_size >= (f6 + 256) * sizeof(float)) {
        float* cand6   = (float*)d_ws;
        float* partial = cand6 + f6;
        knn_split_kernel<4096><<<dim3(NB * 1 * 16), dim3(THREADS), 0, stream>>>(pred, cand6);
        merge_loss_kernel<1><<<dim3(256), dim3(THREADS), 0, stream>>>(cand6, partial);
        final_reduce_kernel<<<dim3(1), dim3(64), 0, stream>>>(partial, out);
    } else {
        float* partial = (float*)d_ws;            // 256 floats
        mono_kernel<<<dim3(256), dim3(THREADS), 0, stream>>>(pred, partial);
        final_reduce_kernel<<<dim3(1), dim3(64), 0, stream>>>(partial, out);
    }
}